// Round 1
// baseline (184.339 us; speedup 1.0000x reference)
//
#include <hip/hip_runtime.h>
#include <math.h>

// Problem sizes (fixed by setup_inputs)
constexpr int BATCH = 64;
constexpr int IN    = 1024;
constexpr int NN    = 2048;   // num_neurons
constexpr int OUTF  = 1024;

constexpr float INV2PI = 0.15915494309189535f;  // 1/(2*pi)
constexpr float SQRT2  = 1.4142135623730951f;

// sin_t + cos_t = sqrt(2)*sin(theta + pi/4); reference LUT-quantizes theta to
// 2pi/4096 steps. We drop the quantization (|err| <= sqrt2*pi/4096 ~ 1.1e-3
// per element -> ~8 absmax on the output vs threshold 26.7), so each element
// is ONE fma + ONE v_sin: a = x*(rcp(1+|W|)/2pi) + (B/2pi + 1/8) [revolutions].

// Butterfly transpose-reduction with COMPILE-TIME trip counts.
template<int M>
__device__ __forceinline__ void butterfly(float* acc, int lane) {
    const bool hi = (lane & M) != 0;
#pragma unroll
    for (int j = 0; j < M; ++j) {
        const float send = hi ? acc[j] : acc[j + M];
        const float recv = __shfl_xor(send, M, 64);
        acc[j] = (hi ? acc[j + M] : acc[j]) + recv;
    }
    if constexpr (M > 1) butterfly<M / 2>(acc, lane);
}

// ---------------- Stage 1: interference ----------------
// LDS-BW analysis of the previous version: per chunk/CU, 512 ds_read_b128
// x 12cyc = 6144 cyc vs sin 4096 cyc/SIMD -> LDS-read-bound (each wave
// streamed 256KB of x for ONE neuron). Fix: 2 neurons per wave -> each
// ds_read_b128 feeds 8 sins, LDS drops to 3072 cyc/chunk, under the sin roof.
// W/B are now prefetched per-chunk into registers (32MB HBM streams under the
// sin shadow instead of a serial prologue).
// Grid 512 blocks x 4 waves; block = 8 neurons x 32 batches (h-half), K=1024.
// LDS 2x32KB double buffer -> 2 blocks/CU -> 2 waves/SIMD (enough: sin pipe
// is throughput-bound with 8 independent sins per bb-iter per wave).

__global__ __launch_bounds__(256)
__attribute__((amdgpu_waves_per_eu(2, 2)))
void k_interf(const float* __restrict__ x, const float* __restrict__ W,
              const float* __restrict__ B, float* __restrict__ part) {
    __shared__ float xs[2][32 * 256];   // double buffer, 2 x 32KB

    const int tid  = threadIdx.x;
    const int lane = tid & 63;
    const int wv   = __builtin_amdgcn_readfirstlane(tid >> 6);   // 0..3
    const int bid  = blockIdx.x;      // 512 blocks
    const int h    = bid & 1;         // batch half
    const int n0   = (bid >> 1) * 8 + wv * 2;   // this wave's neuron pair

    const float* gx = x + (size_t)(h * 32) * IN;   // this block's 32 batch rows

#define STAGE(KC, P)                                                           \
    {                                                                          \
        _Pragma("unroll")                                                      \
        for (int rr = 0; rr < 8; ++rr) {                                       \
            const int r = wv * 8 + rr;  /* wave-uniform LDS base */            \
            __builtin_amdgcn_global_load_lds(                                  \
                (const __attribute__((address_space(1))) unsigned int*)        \
                    (gx + (size_t)r * IN + (KC) * 256 + 4 * lane),             \
                (__attribute__((address_space(3))) unsigned int*)              \
                    &xs[(P)][r * 256],                                         \
                16, 0, 0);                                                     \
        }                                                                      \
    }

    // W/B chunk-0 raw values (iv/bs derived per-chunk; next chunk prefetched
    // during compute so the 32MB W/B stream overlaps the sin work)
    float4 wc[2], bc[2];
#pragma unroll
    for (int j = 0; j < 2; ++j) {
        wc[j] = *(const float4*)&W[(size_t)(n0 + j) * IN + 4 * lane];
        bc[j] = *(const float4*)&B[(size_t)(n0 + j) * IN + 4 * lane];
    }

    float acc[64];   // acc[j*32+bb]: neuron j, batch bb — all indices static
#pragma unroll
    for (int i = 0; i < 64; ++i) acc[i] = 0.0f;

    STAGE(0, 0);
    __syncthreads();   // chunk 0 ready

#pragma unroll 1       // keep code size ~7KB (fits L1I); body is bb-unrolled
    for (int kc = 0; kc < 4; ++kc) {
        const int p = kc & 1;

        float4 wn[2], bn[2];
        if (kc < 3) {   // prefetch next W/B chunk + next x chunk
#pragma unroll
            for (int j = 0; j < 2; ++j) {
                wn[j] = *(const float4*)&W[(size_t)(n0 + j) * IN + (kc + 1) * 256 + 4 * lane];
                bn[j] = *(const float4*)&B[(size_t)(n0 + j) * IN + (kc + 1) * 256 + 4 * lane];
            }
            STAGE(kc + 1, 1 - p);
        }

        // fold this chunk's per-(n,k) math: a = x*iv + bs (revolutions)
        float4 iv[2], bs[2];
#pragma unroll
        for (int j = 0; j < 2; ++j) {
            iv[j].x = INV2PI * __builtin_amdgcn_rcpf(1.0f + fabsf(wc[j].x));
            iv[j].y = INV2PI * __builtin_amdgcn_rcpf(1.0f + fabsf(wc[j].y));
            iv[j].z = INV2PI * __builtin_amdgcn_rcpf(1.0f + fabsf(wc[j].z));
            iv[j].w = INV2PI * __builtin_amdgcn_rcpf(1.0f + fabsf(wc[j].w));
            bs[j].x = fmaf(bc[j].x, INV2PI, 0.125f);
            bs[j].y = fmaf(bc[j].y, INV2PI, 0.125f);
            bs[j].z = fmaf(bc[j].z, INV2PI, 0.125f);
            bs[j].w = fmaf(bc[j].w, INV2PI, 0.125f);
        }

#pragma unroll   // MUST be full: dynamic acc idx -> scratch
        for (int bb = 0; bb < 32; ++bb) {
            const float4 xv = *(const float4*)&xs[p][bb * 256 + 4 * lane];
#pragma unroll
            for (int j = 0; j < 2; ++j) {   // one LDS read serves BOTH neurons
                const float a0 = fmaf(xv.x, iv[j].x, bs[j].x);
                const float a1 = fmaf(xv.y, iv[j].y, bs[j].y);
                const float a2 = fmaf(xv.z, iv[j].z, bs[j].z);
                const float a3 = fmaf(xv.w, iv[j].w, bs[j].w);
                const float t0 = __builtin_amdgcn_sinf(a0);   // sin(2*pi*a)
                const float t1 = __builtin_amdgcn_sinf(a1);
                const float t2 = __builtin_amdgcn_sinf(a2);
                const float t3 = __builtin_amdgcn_sinf(a3);
                acc[j * 32 + bb] += (t0 + t1) + (t2 + t3);
            }
        }
        __syncthreads();   // frees buf p, drains prefetch
        if (kc < 3) {
#pragma unroll
            for (int j = 0; j < 2; ++j) { wc[j] = wn[j]; bc[j] = bn[j]; }
        }
    }
#undef STAGE

    // transpose-reduce 64 values over 64 lanes:
    // lane l ends with acc[l] = (neuron n0 + (l>>5), batch h*32 + (l&31))
    butterfly<32>(acc, lane);

    const int nst = n0 + (lane >> 5);
    part[(size_t)(h * 32 + (lane & 31)) * NN + nst] = acc[0] * SQRT2;
}

// ---------------- Stage 2: projection ----------------
// out[b][o] = sum_n part[b][n] * ow[o][n].  Register outer-product, now
// 8o x 8b per wave with SCALAR accumulators (64 VGPR, vs float4[4][8]=128):
// halves L2 traffic 192MB -> 128MB (~3.7us @ 34.5TB/s), compute 1.7us hidden.
// 1024 waves = 256 blocks x 4; all loads coalesced float4 along n.

__global__ __launch_bounds__(256)
__attribute__((amdgpu_waves_per_eu(2, 2)))
void k_proj(const float* __restrict__ part, const float* __restrict__ ow,
            float* __restrict__ out) {
    const int tid  = threadIdx.x;
    const int lane = tid & 63;
    const int wv   = __builtin_amdgcn_readfirstlane(tid >> 6);
    const int wid  = blockIdx.x * 4 + wv;        // 0..1023
    const int o0   = (wid & 127) * 8;            // 128 o-tiles x 8
    const int b0   = (wid >> 7) * 8;             // 8 b-tiles x 8

    float acc[64];   // acc[o*8+b]
#pragma unroll
    for (int i = 0; i < 64; ++i) acc[i] = 0.0f;

#pragma unroll 1
    for (int it = 0; it < NN / 256; ++it) {      // 8 slabs of 256 n
        const int nb = it * 256 + lane * 4;
        float4 wrow[8], vrow[8];
#pragma unroll
        for (int o = 0; o < 8; ++o)
            wrow[o] = *(const float4*)&ow[(size_t)(o0 + o) * NN + nb];
#pragma unroll
        for (int b = 0; b < 8; ++b)
            vrow[b] = *(const float4*)&part[(size_t)(b0 + b) * NN + nb];
#pragma unroll
        for (int o = 0; o < 8; ++o)
#pragma unroll
            for (int b = 0; b < 8; ++b) {
                float s = acc[o * 8 + b];
                s = fmaf(wrow[o].x, vrow[b].x, s);
                s = fmaf(wrow[o].y, vrow[b].y, s);
                s = fmaf(wrow[o].z, vrow[b].z, s);
                s = fmaf(wrow[o].w, vrow[b].w, s);
                acc[o * 8 + b] = s;
            }
    }

    // cross-lane sum over 64 lanes; lane l ends with acc[l]'s total
    butterfly<32>(acc, lane);

    // l = o*8+b  ->  o = lane>>3, b = lane&7
    out[(size_t)(b0 + (lane & 7)) * OUTF + o0 + (lane >> 3)] = acc[0];
}

extern "C" void kernel_launch(void* const* d_in, const int* in_sizes, int n_in,
                              void* d_out, int out_size, void* d_ws, size_t ws_size,
                              hipStream_t stream) {
    const float* x  = (const float*)d_in[0];
    const float* W  = (const float*)d_in[1];
    const float* B  = (const float*)d_in[2];
    const float* ow = (const float*)d_in[3];
    float* out  = (float*)d_out;
    float* part = (float*)d_ws;    // 512 KB, [b][n]

    k_interf<<<dim3(512), dim3(256), 0, stream>>>(x, W, B, part);
    k_proj  <<<dim3(256), dim3(256), 0, stream>>>(part, ow, out);
}